// Round 8
// baseline (297.520 us; speedup 1.0000x reference)
//
#include <hip/hip_runtime.h>
#include <cfloat>
#include <math.h>

#define BINS   50
#define NB     256          // grid blocks == buckets == chunks
#define NTH    1024
#define NQRB   16           // blocks that also build marginal histograms
#define CH_SM  3906         // small z-chunk for QR blocks (balances their extra work)
#define CH_LG  8073         // z-chunk for the other 240 blocks
#define SWORDS 12208        // ceil(24415/2) u16-packed slice bins (payload = flat>>8)

typedef float nfloat4 __attribute__((ext_vector_type(4)));

// ---- monotone float<->uint encoding; min tracked as atomicMax(~encf) so init=0 ----
__device__ __forceinline__ unsigned encf(float f) {
  unsigned u = __float_as_uint(f);
  return (u & 0x80000000u) ? ~u : (u | 0x80000000u);
}
__device__ __forceinline__ float decf(unsigned u) {
  unsigned v = (u & 0x80000000u) ? (u & 0x7FFFFFFFu) : ~u;
  return __uint_as_float(v);
}

// samples = z @ L^T + mean (bit-identical to all passing rounds)
__device__ __forceinline__ void sample4(nfloat4 zv, const float* L, const float* M,
                                        float& s0, float& s1, float& s2, float& s3) {
  s0 = L[0] * zv.x + M[0];
  s1 = fmaf(L[5], zv.y, L[4] * zv.x) + M[1];
  s2 = fmaf(L[10], zv.z, fmaf(L[9], zv.y, L[8] * zv.x)) + M[2];
  s3 = fmaf(L[15], zv.w, fmaf(L[14], zv.z, fmaf(L[13], zv.y, L[12] * zv.x))) + M[3];
}

__device__ __forceinline__ unsigned dstart(int c) {
  return (c < NQRB) ? (unsigned)(c * CH_SM)
                    : (unsigned)(NQRB * CH_SM + (c - NQRB) * CH_LG);
}

// ticket barrier: RELEASE add (s_waitcnt + wbl2; cheap when nothing dirty),
// relaxed spin, ACQUIRE fence on exit (inv).
__device__ __forceinline__ void gbar_full(unsigned* t) {
  __syncthreads();
  if (threadIdx.x == 0) {
    __hip_atomic_fetch_add(t, 1u, __ATOMIC_RELEASE, __HIP_MEMORY_SCOPE_AGENT);
    while (__hip_atomic_load(t, __ATOMIC_RELAXED, __HIP_MEMORY_SCOPE_AGENT) < (unsigned)NB)
      __builtin_amdgcn_s_sleep(8);
  }
  __syncthreads();
  __builtin_amdgcn_fence(__ATOMIC_ACQUIRE, "agent");
}

__global__ void __launch_bounds__(NTH)
k_one(const float* __restrict__ q, const float* __restrict__ r,
      const float* __restrict__ z, int N, int S, char* ws, float* out)
{
  // ws layout: [0,256) zeroed by hipMemsetAsync each call.
  double*   acc  = (double*)ws;                 //   0: [14] cov raw moments
  double*   sumJ = (double*)(ws + 112);         // 112: [1]
  unsigned* mm   = (unsigned*)(ws + 120);       // 120: [6] qmin~,qmax,rmin~,rmax,smin~,smax
  unsigned* tick = (unsigned*)(ws + 144);       // 144: [4] barriers
  unsigned* Qpart= (unsigned*)(ws + 256);       // [16][2500]
  unsigned* Rpart= (unsigned*)(ws + 160256);    // [16][2500]
  unsigned* Cnt  = (unsigned*)(ws + 320512);    // [256 chunk][256 bucket]
  unsigned short* payload = (unsigned short*)(ws + 582656); // [2000016] chunk-sorted

  __shared__ __align__(16) char smem[49152];    // phase-multiplexed
  __shared__ unsigned sA[NB], sBv[NB];
  __shared__ float    sML[24];                  // mean[4], L[16], qlo,qsc,rlo,rsc
  __shared__ double   sRed[32];
  __shared__ float    sFl[64];
  __shared__ unsigned sFlag;

  const int tid = threadIdx.x, bid = blockIdx.x;
  const int lane = tid & 63, wv = tid >> 6;

  //=============== P1: cov raw moments + q/r min/max (atomics only) =======
  {
    double a[14]; for (int j = 0; j < 14; j++) a[j] = 0.0;
    float qmn = FLT_MAX, qmx = -FLT_MAX, rmn = FLT_MAX, rmx = -FLT_MAX;
    for (int i = bid * NTH + tid; i < N; i += NB * NTH) {
      float2 qv = ((const float2*)q)[i];
      float2 rv = ((const float2*)r)[i];
      qmn = fminf(qmn, fminf(qv.x, qv.y)); qmx = fmaxf(qmx, fmaxf(qv.x, qv.y));
      rmn = fminf(rmn, fminf(rv.x, rv.y)); rmx = fmaxf(rmx, fmaxf(rv.x, rv.y));
      double x0 = qv.x, x1 = qv.y, x2 = rv.x, x3 = rv.y;
      a[0] += x0; a[1] += x1; a[2] += x2; a[3] += x3;
      a[4] += x0*x0; a[5] += x0*x1; a[6] += x0*x2; a[7] += x0*x3;
      a[8] += x1*x1; a[9] += x1*x2; a[10] += x1*x3;
      a[11] += x2*x2; a[12] += x2*x3; a[13] += x3*x3;
    }
    double* wred = (double*)smem;               // [16][14]
    for (int j = 0; j < 14; j++) {
      double v = a[j];
      for (int o = 32; o > 0; o >>= 1) v += __shfl_down(v, o);
      if (lane == 0) wred[wv * 14 + j] = v;
    }
    for (int o = 32; o > 0; o >>= 1) {
      qmn = fminf(qmn, __shfl_down(qmn, o)); qmx = fmaxf(qmx, __shfl_down(qmx, o));
      rmn = fminf(rmn, __shfl_down(rmn, o)); rmx = fmaxf(rmx, __shfl_down(rmx, o));
    }
    if (lane == 0) { sFl[wv] = qmn; sFl[16+wv] = qmx; sFl[32+wv] = rmn; sFl[48+wv] = rmx; }
    __syncthreads();
    if (tid < 14) {
      double s = 0; for (int w = 0; w < 16; w++) s += wred[w * 14 + tid];
      atomicAdd(&acc[tid], s);
    } else if (tid >= 16 && tid < 20) {
      int k = tid - 16;
      bool ismn = (k == 0) || (k == 2);
      float v = sFl[k * 16];
      for (int w = 1; w < 16; w++) {
        float x = sFl[k * 16 + w];
        v = ismn ? fminf(v, x) : fmaxf(v, x);
      }
      atomicMax(&mm[k], ismn ? ~encf(v) : encf(v));
    }
  }
  gbar_full(&tick[0]);   // ---- A (atomic-only data crosses)

  //=============== P2: redundant Cholesky + z-minmax + QR hist ===========
  if (tid == 0) {
    double sD[14], mean[4];
    for (int j = 0; j < 14; j++) sD[j] = acc[j];
    for (int j = 0; j < 4; j++) mean[j] = sD[j] / (double)N;
    double cov[4][4]; int t4 = 4;
    for (int i = 0; i < 4; i++)
      for (int j = i; j < 4; j++) {
        double c = (sD[t4] - (double)N * mean[i] * mean[j]) / (double)(N - 1);
        if (i == j) c += 1e-6;
        cov[i][j] = c; cov[j][i] = c; t4++;
      }
    double L[4][4] = {};
    for (int i = 0; i < 4; i++)
      for (int j = 0; j <= i; j++) {
        double s = cov[i][j];
        for (int k = 0; k < j; k++) s -= L[i][k] * L[j][k];
        if (i == j) L[i][j] = sqrt(s);
        else        L[i][j] = s / L[j][j];
      }
    for (int i = 0; i < 4; i++) {
      sML[i] = (float)mean[i];
      for (int j = 0; j < 4; j++) sML[4 + i*4 + j] = (float)L[i][j];
    }
    float qlo = decf(~mm[0]), qhi = decf(mm[1]);
    float rlo = decf(~mm[2]), rhi = decf(mm[3]);
    sML[20] = qlo; sML[21] = (float)BINS / (qhi - qlo);
    sML[22] = rlo; sML[23] = (float)BINS / (rhi - rlo);
  }
  __syncthreads();
  float l[16], m[4];
  for (int i = 0; i < 16; i++) l[i] = sML[4 + i];
  for (int i = 0; i < 4;  i++) m[i] = sML[i];

  unsigned st = dstart(bid);
  unsigned en = min(dstart(bid + 1), (unsigned)S);
  {
    float mn = FLT_MAX, mx = -FLT_MAX;
    const nfloat4* z4 = (const nfloat4*)z;
    for (unsigned i = st + tid; i < en; i += NTH) {
      nfloat4 zv = z4[i];
      float s0, s1, s2, s3; sample4(zv, l, m, s0, s1, s2, s3);
      mn = fminf(mn, fminf(fminf(s0, s1), fminf(s2, s3)));
      mx = fmaxf(mx, fmaxf(fmaxf(s0, s1), fmaxf(s2, s3)));
    }
    for (int o = 32; o > 0; o >>= 1) {
      mn = fminf(mn, __shfl_down(mn, o)); mx = fmaxf(mx, __shfl_down(mx, o));
    }
    if (lane == 0) { sFl[wv] = mn; sFl[16 + wv] = mx; }
    __syncthreads();
    if (tid == 0) {
      for (int w = 1; w < 16; w++) { mn = fminf(mn, sFl[w]); mx = fmaxf(mx, sFl[16+w]); }
      mn = fminf(mn, sFl[0]); mx = fmaxf(mx, sFl[16]);
      atomicMax(&mm[4], ~encf(mn));
      atomicMax(&mm[5], encf(mx));
    }
  }
  // arrive B early, then QR blocks do their marginal hist while others spin
  __syncthreads();
  if (tid == 0)
    __hip_atomic_fetch_add(&tick[1], 1u, __ATOMIC_RELEASE, __HIP_MEMORY_SCOPE_AGENT);
  if (bid < NQRB) {
    int* hq = (int*)smem;            // [2500]
    int* hr = (int*)(smem + 10240);  // [2500]
    for (int i = tid; i < 2500; i += NTH) { hq[i] = 0; hr[i] = 0; }
    __syncthreads();
    float qlo = sML[20], qsc = sML[21], rlo = sML[22], rsc = sML[23];
    int r0 = bid * (N / NQRB), r1 = (bid + 1) * (N / NQRB);
    for (int i = r0 + tid; i < r1; i += NTH) {
      float2 qv = ((const float2*)q)[i];
      float2 rv = ((const float2*)r)[i];
      int a = min(max((int)floorf((qv.x - qlo) * qsc), 0), BINS - 1);
      int b = min(max((int)floorf((qv.y - qlo) * qsc), 0), BINS - 1);
      atomicAdd(&hq[a * BINS + b], 1);
      a = min(max((int)floorf((rv.x - rlo) * rsc), 0), BINS - 1);
      b = min(max((int)floorf((rv.y - rlo) * rsc), 0), BINS - 1);
      atomicAdd(&hr[a * BINS + b], 1);
    }
    __syncthreads();
    for (int i = tid; i < 2500; i += NTH) {
      Qpart[bid * 2500 + i] = (unsigned)hq[i];   // plain stores; released at C
      Rpart[bid * 2500 + i] = (unsigned)hr[i];
    }
  }
  if (tid == 0)
    while (__hip_atomic_load(&tick[1], __ATOMIC_RELAXED, __HIP_MEMORY_SCOPE_AGENT) < (unsigned)NB)
      __builtin_amdgcn_s_sleep(8);
  __syncthreads();
  __builtin_amdgcn_fence(__ATOMIC_ACQUIRE, "agent");   // ---- B

  //=============== P3: bin + LDS counting sort + coalesced chunk write ===
  {
    float lo = decf(~mm[4]);
    float hi = decf(mm[5]);
    float sc = (float)BINS / (hi - lo);
    unsigned short* pays = (unsigned short*)smem;            // [8080]
    unsigned short* ptmp = (unsigned short*)(smem + 16160);  // [8080]
    unsigned char*  bb   = (unsigned char*)(smem + 32320);   // [8080]
    unsigned* cnt    = (unsigned*)(smem + 40400);            // [256]
    unsigned* lbase  = (unsigned*)(smem + 41424);            // [256]
    unsigned* cursor = (unsigned*)(smem + 42448);            // [256]
    if (tid < NB) cnt[tid] = 0;
    __syncthreads();
    int len = (int)(en - st);
    const nfloat4* z4 = (const nfloat4*)z;
    for (int j = tid; j < len; j += NTH) {
      nfloat4 zv = z4[st + j];
      float s0, s1, s2, s3; sample4(zv, l, m, s0, s1, s2, s3);
      int i0 = min(max((int)floorf((s0 - lo) * sc), 0), BINS - 1);
      int i1 = min(max((int)floorf((s1 - lo) * sc), 0), BINS - 1);
      int i2 = min(max((int)floorf((s2 - lo) * sc), 0), BINS - 1);
      int i3 = min(max((int)floorf((s3 - lo) * sc), 0), BINS - 1);
      unsigned flat = (unsigned)(((i0*BINS + i1)*BINS + i2)*BINS + i3);
      ptmp[j] = (unsigned short)(flat >> 8);
      bb[j]   = (unsigned char)(flat & 255u);
      atomicAdd(&cnt[flat & 255u], 1u);
    }
    __syncthreads();
    if (tid < NB) sA[tid] = cnt[tid];
    __syncthreads();
    for (int off = 1; off < NB; off <<= 1) {
      unsigned x = (tid < NB && tid >= off) ? sA[tid - off] : 0u;
      __syncthreads();
      if (tid < NB) sA[tid] += x;
      __syncthreads();
    }
    if (tid < NB) { lbase[tid] = sA[tid] - cnt[tid]; cursor[tid] = 0; }
    __syncthreads();
    for (int j = tid; j < len; j += NTH) {
      unsigned b = bb[j];
      unsigned pos = lbase[b] + atomicAdd(&cursor[b], 1u);
      pays[pos] = ptmp[j];
    }
    __syncthreads();
    for (int p = tid; p < len; p += NTH) payload[st + p] = pays[p];  // coalesced
    if (tid < NB) Cnt[bid * NB + tid] = cnt[tid];
  }
  gbar_full(&tick[2]);   // ---- C (the one barrier with real dirty data: ~4 MB)

  //=============== P4: per-bucket gather + LDS hist + entropy ============
  {
    unsigned* shist = (unsigned*)smem;    // [SWORDS]
    if (tid < NB) {
      unsigned lb = 0;
      const unsigned* row = &Cnt[tid * NB];
      for (int b2 = 0; b2 < bid; b2++) lb += row[b2];   // within-chunk prefix
      sBv[tid] = lb; sA[tid] = row[bid];
    }
    for (int i = tid; i < SWORDS; i += NTH) shist[i] = 0u;
    __syncthreads();
    {
      int c = tid >> 2, j0 = tid & 3;   // 4 threads per chunk-run
      unsigned base2 = dstart(c) + sBv[c];
      unsigned lenc = sA[c];
      for (unsigned k = j0; k < lenc; k += 4) {
        unsigned p = payload[base2 + k];   // < 24415
        atomicAdd(&shist[p >> 1], (p & 1u) ? 65536u : 1u);
      }
    }
    __syncthreads();
    double local = 0.0;
    for (int i = tid; i < SWORDS; i += NTH) {
      unsigned w = shist[i];
      unsigned c0 = w & 0xFFFFu, c1 = w >> 16;
      if (c0 > 1) local += (double)c0 * log((double)c0);
      if (c1 > 1) local += (double)c1 * log((double)c1);
    }
    for (int o = 32; o > 0; o >>= 1) local += __shfl_down(local, o);
    if (lane == 0) sRed[wv] = local;
    __syncthreads();
    if (tid == 0) {
      double s = 0; for (int w = 0; w < 16; w++) s += sRed[w];
      atomicAdd(sumJ, s);
    }
  }
  // ---- D: last block finalizes
  __syncthreads();
  if (tid == 0) {
    unsigned prev = __hip_atomic_fetch_add(&tick[3], 1u, __ATOMIC_ACQ_REL,
                                           __HIP_MEMORY_SCOPE_AGENT);
    sFlag = (prev == (unsigned)(NB - 1)) ? 1u : 0u;
  }
  __syncthreads();
  if (!sFlag) return;
  __builtin_amdgcn_fence(__ATOMIC_ACQUIRE, "agent");
  {
    double lq = 0.0, lr = 0.0;
    for (int bin = tid; bin < 2500; bin += NTH) {
      unsigned cq = 0, cr = 0;
      for (int k = 0; k < NQRB; k++) {
        cq += Qpart[k * 2500 + bin];
        cr += Rpart[k * 2500 + bin];
      }
      if (cq > 1) lq += (double)cq * log((double)cq);
      if (cr > 1) lr += (double)cr * log((double)cr);
    }
    for (int o = 32; o > 0; o >>= 1) { lq += __shfl_down(lq, o); lr += __shfl_down(lr, o); }
    if (lane == 0) { sRed[wv] = lq; sRed[16 + wv] = lr; }
    __syncthreads();
    if (tid == 0) {
      double sq = 0, sr = 0;
      for (int w = 0; w < 16; w++) { sq += sRed[w]; sr += sRed[16 + w]; }
      double sJ = *sumJ;
      double HT = log((double)N) - sq / (double)N;
      double HI = log((double)N) - sr / (double)N;
      double HJ = log((double)S) - sJ / (double)S;
      double val = HJ / (HT + HI);
      val = val < 0.0 ? 0.0 : (val > 1.0 ? 1.0 : val);
      out[0] = (float)val;
    }
  }
}

extern "C" void kernel_launch(void* const* d_in, const int* in_sizes, int n_in,
                              void* d_out, int out_size, void* d_ws, size_t ws_size,
                              hipStream_t stream) {
  const float* q = (const float*)d_in[0];
  const float* r = (const float*)d_in[1];
  const float* z = (const float*)d_in[2];
  int N = in_sizes[0] / 2;   // 200000
  int S = in_sizes[2] / 4;   // 2000000
  char* ws = (char*)d_ws;
  float* out = (float*)d_out;

  // zero control region (acc, sumJ, mm, tickets) — everything zero-inits
  hipMemsetAsync(ws, 0, 256, stream);

  void* args[] = { (void*)&q, (void*)&r, (void*)&z, (void*)&N, (void*)&S,
                   (void*)&ws, (void*)&out };
  hipLaunchCooperativeKernel((const void*)k_one, dim3(NB), dim3(NTH),
                             args, 0, stream);
}

// Round 9
// 160.751 us; speedup vs baseline: 1.8508x; 1.8508x over previous
//
#include <hip/hip_runtime.h>
#include <cfloat>
#include <math.h>

#define BINS   50
#define NB     256          // buckets == chunks == most grids
#define NTH    1024
#define NZB    512          // z-minmax blocks in k_C
#define NQRB   16           // marginal-histogram blocks in k_C
#define CHUNK  7813         // ceil(2e6 / 256)
#define KCAP   7936         // LDS sort capacity >= CHUNK
#define SWORDS 12208        // ceil(24415/2) u16-packed slice bins (payload = flat>>8)

typedef float nfloat4 __attribute__((ext_vector_type(4)));

// ---- monotone float<->uint encoding for atomic min/max on floats ----
__device__ __forceinline__ unsigned encf(float f) {
  unsigned u = __float_as_uint(f);
  return (u & 0x80000000u) ? ~u : (u | 0x80000000u);
}
__device__ __forceinline__ float decf(unsigned u) {
  unsigned v = (u & 0x80000000u) ? (u & 0x7FFFFFFFu) : ~u;
  return __uint_as_float(v);
}

// samples = z @ L^T + mean (bit-identical to all passing rounds)
__device__ __forceinline__ void sample4(nfloat4 zv, const float* L, const float* M,
                                        float& s0, float& s1, float& s2, float& s3) {
  s0 = L[0] * zv.x + M[0];
  s1 = fmaf(L[5], zv.y, L[4] * zv.x) + M[1];
  s2 = fmaf(L[10], zv.z, fmaf(L[9], zv.y, L[8] * zv.x)) + M[2];
  s3 = fmaf(L[15], zv.w, fmaf(L[14], zv.z, fmaf(L[13], zv.y, L[12] * zv.x))) + M[3];
}

// waves 0..13 sum Bpart rows -> sD[14]; waves 14,15 min/max QRmm -> sQR[4];
// thread 0: Cholesky -> sML[24]. (verified in R7)
__device__ __forceinline__ void reduce_and_chol(const double* Bpart, const float* QRmm,
                                                int n, double* sD, float* sQR, float* sML) {
  int tid = threadIdx.x, ln = tid & 63, wv = tid >> 6;
  if (wv < 14) {
    double s = 0;
    for (int b = ln; b < NB; b += 64) s += Bpart[wv * NB + b];
    for (int o = 32; o > 0; o >>= 1) s += __shfl_down(s, o);
    if (ln == 0) sD[wv] = s;
  } else {
    int k0 = (wv == 14) ? 0 : 2;
    for (int k2 = k0; k2 < k0 + 2; k2++) {
      bool ismn = (k2 == 0) || (k2 == 2);
      float v = ismn ? FLT_MAX : -FLT_MAX;
      for (int b = ln; b < NB; b += 64) {
        float x = QRmm[k2 * NB + b];
        v = ismn ? fminf(v, x) : fmaxf(v, x);
      }
      for (int o = 32; o > 0; o >>= 1) {
        float x = __shfl_down(v, o);
        v = ismn ? fminf(v, x) : fmaxf(v, x);
      }
      if (ln == 0) sQR[k2] = v;
    }
  }
  __syncthreads();
  if (tid == 0) {
    double mean[4];
    for (int j = 0; j < 4; j++) mean[j] = sD[j] / (double)n;
    double cov[4][4]; int t4 = 4;
    for (int i = 0; i < 4; i++)
      for (int j = i; j < 4; j++) {
        double c = (sD[t4] - (double)n * mean[i] * mean[j]) / (double)(n - 1);
        if (i == j) c += 1e-6;
        cov[i][j] = c; cov[j][i] = c; t4++;
      }
    double L[4][4] = {};
    for (int i = 0; i < 4; i++)
      for (int j = 0; j <= i; j++) {
        double s = cov[i][j];
        for (int k = 0; k < j; k++) s -= L[i][k] * L[j][k];
        if (i == j) L[i][j] = sqrt(s);
        else        L[i][j] = s / L[j][j];
      }
    for (int i = 0; i < 4; i++) {
      sML[i] = (float)mean[i];
      for (int j = 0; j < 4; j++) sML[4 + i*4 + j] = (float)L[i][j];
    }
    float qlo = sQR[0], qhi = sQR[1], rlo = sQR[2], rhi = sQR[3];
    sML[20] = qlo; sML[21] = (float)BINS / (qhi - qlo);
    sML[22] = rlo; sML[23] = (float)BINS / (rhi - rlo);
  }
  __syncthreads();
}

// ============ k_A: cov raw moments + q/r min-max partials; init encs/ticket
__global__ void __launch_bounds__(256)
k_A(const float* __restrict__ q, const float* __restrict__ r, int n,
    double* Bpart, float* QRmm, unsigned* encs, unsigned* ticket) {
  double a[14] = {0,0,0,0,0,0,0,0,0,0,0,0,0,0};
  float qmn = FLT_MAX, qmx = -FLT_MAX, rmn = FLT_MAX, rmx = -FLT_MAX;
  int stride = gridDim.x * blockDim.x;
  for (int i = blockIdx.x * blockDim.x + threadIdx.x; i < n; i += stride) {
    float2 qv = ((const float2*)q)[i];
    float2 rv = ((const float2*)r)[i];
    qmn = fminf(qmn, fminf(qv.x, qv.y)); qmx = fmaxf(qmx, fmaxf(qv.x, qv.y));
    rmn = fminf(rmn, fminf(rv.x, rv.y)); rmx = fmaxf(rmx, fmaxf(rv.x, rv.y));
    double x0 = qv.x, x1 = qv.y, x2 = rv.x, x3 = rv.y;
    a[0] += x0; a[1] += x1; a[2] += x2; a[3] += x3;
    a[4] += x0*x0; a[5] += x0*x1; a[6] += x0*x2; a[7] += x0*x3;
    a[8] += x1*x1; a[9] += x1*x2; a[10] += x1*x3;
    a[11] += x2*x2; a[12] += x2*x3; a[13] += x3*x3;
  }
  __shared__ double sh[4][14];
  __shared__ float shf[4][4];
  int lane = threadIdx.x & 63, wid = threadIdx.x >> 6;
  for (int j = 0; j < 14; j++) {
    double v = a[j];
    for (int o = 32; o > 0; o >>= 1) v += __shfl_down(v, o);
    if (lane == 0) sh[wid][j] = v;
  }
  for (int o = 32; o > 0; o >>= 1) {
    qmn = fminf(qmn, __shfl_down(qmn, o)); qmx = fmaxf(qmx, __shfl_down(qmx, o));
    rmn = fminf(rmn, __shfl_down(rmn, o)); rmx = fmaxf(rmx, __shfl_down(rmx, o));
  }
  if (lane == 0) { shf[wid][0] = qmn; shf[wid][1] = qmx; shf[wid][2] = rmn; shf[wid][3] = rmx; }
  __syncthreads();
  if (threadIdx.x < 14) {
    double t = sh[0][threadIdx.x] + sh[1][threadIdx.x] + sh[2][threadIdx.x] + sh[3][threadIdx.x];
    Bpart[threadIdx.x * NB + blockIdx.x] = t;
  } else if (threadIdx.x >= 16 && threadIdx.x < 20) {
    int k = threadIdx.x - 16;
    float v;
    if (k == 0)      v = fminf(fminf(shf[0][0], shf[1][0]), fminf(shf[2][0], shf[3][0]));
    else if (k == 1) v = fmaxf(fmaxf(shf[0][1], shf[1][1]), fmaxf(shf[2][1], shf[3][1]));
    else if (k == 2) v = fminf(fminf(shf[0][2], shf[1][2]), fminf(shf[2][2], shf[3][2]));
    else             v = fmaxf(fmaxf(shf[0][3], shf[1][3]), fmaxf(shf[2][3], shf[3][3]));
    QRmm[k * NB + blockIdx.x] = v;
  } else if (blockIdx.x == 0 && threadIdx.x == 32) {
    encs[0] = 0xFFFFFFFFu; encs[1] = 0u;
    ticket[0] = 0u;
  }
}

// ============ k_C: redundant reduce+Cholesky; blocks<NZB: sample minmax;
//              blocks >=NZB: marginal QR histograms (partials)
__global__ void __launch_bounds__(1024)
k_C(const double* __restrict__ Bpart, const float* __restrict__ QRmm,
    const float* __restrict__ z, int S,
    const float* __restrict__ q, const float* __restrict__ r, int n,
    float* meanL, unsigned* encs, unsigned* Qpart, unsigned* Rpart) {
  __shared__ double sD[14];
  __shared__ float sQR[4];
  __shared__ float sML[24];
  __shared__ int shQ[2500];
  __shared__ int shR[2500];
  reduce_and_chol(Bpart, QRmm, n, sD, sQR, sML);
  int tid = threadIdx.x, bid = blockIdx.x;
  if (tid == 0 && bid == 0) {    // publish for k_DF
    for (int i = 0; i < 24; i++) meanL[i] = sML[i];
  }
  if (bid < NZB) {
    float l[16], m[4];
    for (int i = 0; i < 16; i++) l[i] = sML[4 + i];
    for (int i = 0; i < 4;  i++) m[i] = sML[i];
    float mn = FLT_MAX, mx = -FLT_MAX;
    const nfloat4* z4 = (const nfloat4*)z;
    int stride = NZB * NTH;
    for (int i = bid * NTH + tid; i < S; i += stride) {
      nfloat4 zv = z4[i];
      float s0, s1, s2, s3; sample4(zv, l, m, s0, s1, s2, s3);
      mn = fminf(mn, fminf(fminf(s0, s1), fminf(s2, s3)));
      mx = fmaxf(mx, fmaxf(fmaxf(s0, s1), fmaxf(s2, s3)));
    }
    for (int o = 32; o > 0; o >>= 1) {
      mn = fminf(mn, __shfl_down(mn, o)); mx = fmaxf(mx, __shfl_down(mx, o));
    }
    __shared__ float shmn[16], shmx[16];
    int lane = tid & 63, wid = tid >> 6;
    if (lane == 0) { shmn[wid] = mn; shmx[wid] = mx; }
    __syncthreads();
    if (tid == 0) {
      for (int w = 0; w < 16; w++) { mn = fminf(mn, shmn[w]); mx = fmaxf(mx, shmx[w]); }
      atomicMin(&encs[0], encf(mn));
      atomicMax(&encs[1], encf(mx));
    }
  } else {
    int qb = bid - NZB;    // 0..15
    for (int i = tid; i < 2500; i += NTH) { shQ[i] = 0; shR[i] = 0; }
    __syncthreads();
    float qlo = sML[20], qsc = sML[21], rlo = sML[22], rsc = sML[23];
    int stride = NQRB * NTH;
    for (int i = qb * NTH + tid; i < n; i += stride) {
      float2 qv = ((const float2*)q)[i];
      float2 rv = ((const float2*)r)[i];
      int a = min(max((int)floorf((qv.x - qlo) * qsc), 0), BINS - 1);
      int b = min(max((int)floorf((qv.y - qlo) * qsc), 0), BINS - 1);
      atomicAdd(&shQ[a*BINS + b], 1);
      a = min(max((int)floorf((rv.x - rlo) * rsc), 0), BINS - 1);
      b = min(max((int)floorf((rv.y - rlo) * rsc), 0), BINS - 1);
      atomicAdd(&shR[a*BINS + b], 1);
    }
    __syncthreads();
    for (int i = tid; i < 2500; i += NTH) {
      Qpart[qb*2500 + i] = (unsigned)shQ[i];
      Rpart[qb*2500 + i] = (unsigned)shR[i];
    }
  }
}

// ============ k_DF: bin own chunk + LDS counting sort + coalesced write
__global__ void __launch_bounds__(1024)
k_DF(const float* __restrict__ z, int S,
     const float* __restrict__ meanL, const unsigned* __restrict__ encs,
     unsigned short* __restrict__ payload, unsigned* __restrict__ Cnt) {
  __shared__ unsigned short ptmp[KCAP];   // 15872 B
  __shared__ unsigned short pays[KCAP];   // 15872 B
  __shared__ unsigned char  bb[KCAP];     //  7936 B
  __shared__ unsigned cnt[NB], sA[NB], lbase[NB], cursor[NB];
  __shared__ float sL[16], sM[4], sPar[2];
  int tid = threadIdx.x, bid = blockIdx.x;
  if (tid < 16) sL[tid] = meanL[4 + tid];
  if (tid < 4)  sM[tid] = meanL[tid];
  if (tid < NB) cnt[tid] = 0;
  if (tid == 0) {
    float lo = decf(encs[0]), hi = decf(encs[1]);
    sPar[0] = lo; sPar[1] = (float)BINS / (hi - lo);
  }
  __syncthreads();
  float lo = sPar[0], sc = sPar[1];
  int st = bid * CHUNK;
  int en = min(st + CHUNK, S);
  int len = en - st;
  const nfloat4* z4 = (const nfloat4*)z;
  for (int j = tid; j < len; j += NTH) {
    nfloat4 zv = z4[st + j];
    float s0, s1, s2, s3; sample4(zv, sL, sM, s0, s1, s2, s3);
    int i0 = min(max((int)floorf((s0 - lo) * sc), 0), BINS - 1);
    int i1 = min(max((int)floorf((s1 - lo) * sc), 0), BINS - 1);
    int i2 = min(max((int)floorf((s2 - lo) * sc), 0), BINS - 1);
    int i3 = min(max((int)floorf((s3 - lo) * sc), 0), BINS - 1);
    unsigned flat = (unsigned)(((i0*BINS + i1)*BINS + i2)*BINS + i3);
    ptmp[j] = (unsigned short)(flat >> 8);
    bb[j]   = (unsigned char)(flat & 255u);
    atomicAdd(&cnt[flat & 255u], 1u);
  }
  __syncthreads();
  if (tid < NB) sA[tid] = cnt[tid];
  __syncthreads();
  for (int off = 1; off < NB; off <<= 1) {
    unsigned x = (tid < NB && tid >= off) ? sA[tid - off] : 0u;
    __syncthreads();
    if (tid < NB) sA[tid] += x;
    __syncthreads();
  }
  if (tid < NB) { lbase[tid] = sA[tid] - cnt[tid]; cursor[tid] = 0; }
  __syncthreads();
  for (int j = tid; j < len; j += NTH) {
    unsigned b = bb[j];
    unsigned pos = lbase[b] + atomicAdd(&cursor[b], 1u);
    pays[pos] = ptmp[j];
  }
  __syncthreads();
  for (int p = tid; p < len; p += NTH) payload[st + p] = pays[p];  // coalesced
  if (tid < NB) Cnt[bid * NB + tid] = cnt[tid];
}

// ============ k_G: per-bucket gather + LDS hist + entropy; last block final
__global__ void __launch_bounds__(1024)
k_G(const unsigned short* __restrict__ payload, const unsigned* __restrict__ Cnt,
    const unsigned* __restrict__ Qpart, const unsigned* __restrict__ Rpart,
    double* sumJpart, unsigned* ticket, int n, int S, float* out) {
  __shared__ unsigned shist[SWORDS];    // 48832 B
  __shared__ unsigned sA[NB], sBv[NB];
  __shared__ double sRed[48];
  __shared__ unsigned sFlag;
  int tid = threadIdx.x, bid = blockIdx.x;
  int lane = tid & 63, wv = tid >> 6;
  if (tid < NB) {
    unsigned lb = 0;
    const unsigned* row = &Cnt[tid * NB];    // chunk tid's bucket counts
    for (int b2 = 0; b2 < bid; b2++) lb += row[b2];
    sBv[tid] = lb; sA[tid] = row[bid];
  }
  for (int i = tid; i < SWORDS; i += NTH) shist[i] = 0u;
  __syncthreads();
  {
    int c = tid >> 2, j0 = tid & 3;          // 4 threads per chunk-run
    unsigned base2 = (unsigned)(c * CHUNK) + sBv[c];
    unsigned lenc = sA[c];
    for (unsigned k = j0; k < lenc; k += 4) {
      unsigned p = payload[base2 + k];       // < 24415
      atomicAdd(&shist[p >> 1], (p & 1u) ? 65536u : 1u);
    }
  }
  __syncthreads();
  double local = 0.0;
  for (int i = tid; i < SWORDS; i += NTH) {
    unsigned w = shist[i];
    unsigned c0 = w & 0xFFFFu, c1 = w >> 16;
    if (c0 > 1) local += (double)c0 * log((double)c0);
    if (c1 > 1) local += (double)c1 * log((double)c1);
  }
  for (int o = 32; o > 0; o >>= 1) local += __shfl_down(local, o);
  if (lane == 0) sRed[wv] = local;
  __syncthreads();
  if (tid == 0) {
    double s = 0; for (int w = 0; w < 16; w++) s += sRed[w];
    sumJpart[bid] = s;
    __threadfence();
    sFlag = (atomicAdd(ticket, 1u) == NB - 1) ? 1u : 0u;
  }
  __syncthreads();
  if (!sFlag) return;
  // ---------- last block: final reduction + output ----------
  __threadfence();
  double v = 0.0;
  if (tid < NB)
    v = __hip_atomic_load(&sumJpart[tid], __ATOMIC_RELAXED, __HIP_MEMORY_SCOPE_AGENT);
  for (int o = 32; o > 0; o >>= 1) v += __shfl_down(v, o);
  if (lane == 0) sRed[wv] = v;
  double lq = 0.0, lr = 0.0;
  for (int bin = tid; bin < 2500; bin += NTH) {
    unsigned cq = 0, cr = 0;
    for (int k = 0; k < NQRB; k++) { cq += Qpart[k*2500 + bin]; cr += Rpart[k*2500 + bin]; }
    if (cq > 1) lq += (double)cq * log((double)cq);
    if (cr > 1) lr += (double)cr * log((double)cr);
  }
  for (int o = 32; o > 0; o >>= 1) { lq += __shfl_down(lq, o); lr += __shfl_down(lr, o); }
  if (lane == 0) { sRed[16 + wv] = lq; sRed[32 + wv] = lr; }
  __syncthreads();
  if (tid == 0) {
    double sJ = 0, sq = 0, sr = 0;
    for (int w = 0; w < 16; w++) { sJ += sRed[w]; sq += sRed[16+w]; sr += sRed[32+w]; }
    double HT = log((double)n) - sq / (double)n;
    double HI = log((double)n) - sr / (double)n;
    double HJ = log((double)S) - sJ / (double)S;
    double val = HJ / (HT + HI);
    val = val < 0.0 ? 0.0 : (val > 1.0 ? 1.0 : val);
    out[0] = (float)val;
  }
}

extern "C" void kernel_launch(void* const* d_in, const int* in_sizes, int n_in,
                              void* d_out, int out_size, void* d_ws, size_t ws_size,
                              hipStream_t stream) {
  const float* q = (const float*)d_in[0];
  const float* r = (const float*)d_in[1];
  const float* z = (const float*)d_in[2];
  int N = in_sizes[0] / 2;   // 200000 rows
  int S = in_sizes[2] / 4;   // 2000000 samples

  // workspace layout (bytes), total ~4.6 MB:
  char* base = (char*)d_ws;
  double*   Bpart    = (double*)base;                     //      0: [14][256]
  float*    QRmm     = (float*)(base + 28672);            //  28672: [4][256]
  float*    meanL    = (float*)(base + 32768);            //  32768: [24]
  unsigned* encs     = (unsigned*)(base + 32896);         //  32896: [2]
  unsigned* ticket   = (unsigned*)(base + 32904);         //  32904: [1]
  double*   sumJpart = (double*)(base + 33024);           //  33024: [256]
  unsigned* Qpart    = (unsigned*)(base + 35072);         //  35072: [16][2500]
  unsigned* Rpart    = (unsigned*)(base + 195072);        // [16][2500]
  unsigned* Cnt      = (unsigned*)(base + 355072);        // [256 chunk][256 bucket]
  unsigned short* payload = (unsigned short*)(base + 617216); // [2M] chunk-sorted (4 MB)

  k_A<<<NB, 256, 0, stream>>>(q, r, N, Bpart, QRmm, encs, ticket);
  k_C<<<NZB + NQRB, 1024, 0, stream>>>(Bpart, QRmm, z, S, q, r, N,
                                       meanL, encs, Qpart, Rpart);
  k_DF<<<NB, 1024, 0, stream>>>(z, S, meanL, encs, payload, Cnt);
  k_G<<<NB, 1024, 0, stream>>>(payload, Cnt, Qpart, Rpart,
                               sumJpart, ticket, N, S, (float*)d_out);
}

// Round 10
// 143.919 us; speedup vs baseline: 2.0673x; 1.1170x over previous
//
#include <hip/hip_runtime.h>
#include <cfloat>
#include <math.h>

#define BINS    50
#define NCH     256         // z chunks (k_DF blocks)
#define NBK     512         // buckets (k_G blocks); bucket = flat & 511
#define NTH     1024
#define NZB     512         // z-minmax blocks in k_C
#define NQRB    16          // marginal-histogram blocks in k_C
#define CHUNK   7813        // ceil(2e6 / 256)
#define KCAP    7936        // LDS sort capacity >= CHUNK
#define SWORDS2 6104        // ceil(12208/2) u16-packed slice bins (payload = flat>>9)

typedef float nfloat4 __attribute__((ext_vector_type(4)));

// ---- monotone float<->uint encoding for atomic min/max on floats ----
__device__ __forceinline__ unsigned encf(float f) {
  unsigned u = __float_as_uint(f);
  return (u & 0x80000000u) ? ~u : (u | 0x80000000u);
}
__device__ __forceinline__ float decf(unsigned u) {
  unsigned v = (u & 0x80000000u) ? (u & 0x7FFFFFFFu) : ~u;
  return __uint_as_float(v);
}

// samples = z @ L^T + mean (bit-identical to all passing rounds)
__device__ __forceinline__ void sample4(nfloat4 zv, const float* L, const float* M,
                                        float& s0, float& s1, float& s2, float& s3) {
  s0 = L[0] * zv.x + M[0];
  s1 = fmaf(L[5], zv.y, L[4] * zv.x) + M[1];
  s2 = fmaf(L[10], zv.z, fmaf(L[9], zv.y, L[8] * zv.x)) + M[2];
  s3 = fmaf(L[15], zv.w, fmaf(L[14], zv.z, fmaf(L[13], zv.y, L[12] * zv.x))) + M[3];
}

// waves 0..13 sum Bpart rows -> sD[14]; waves 14,15 min/max QRmm -> sQR[4];
// thread 0: Cholesky -> sML[24]. (verified R7/R9)
__device__ __forceinline__ void reduce_and_chol(const double* Bpart, const float* QRmm,
                                                int n, double* sD, float* sQR, float* sML) {
  int tid = threadIdx.x, ln = tid & 63, wv = tid >> 6;
  if (wv < 14) {
    double s = 0;
    for (int b = ln; b < NCH; b += 64) s += Bpart[wv * NCH + b];
    for (int o = 32; o > 0; o >>= 1) s += __shfl_down(s, o);
    if (ln == 0) sD[wv] = s;
  } else {
    int k0 = (wv == 14) ? 0 : 2;
    for (int k2 = k0; k2 < k0 + 2; k2++) {
      bool ismn = (k2 == 0) || (k2 == 2);
      float v = ismn ? FLT_MAX : -FLT_MAX;
      for (int b = ln; b < NCH; b += 64) {
        float x = QRmm[k2 * NCH + b];
        v = ismn ? fminf(v, x) : fmaxf(v, x);
      }
      for (int o = 32; o > 0; o >>= 1) {
        float x = __shfl_down(v, o);
        v = ismn ? fminf(v, x) : fmaxf(v, x);
      }
      if (ln == 0) sQR[k2] = v;
    }
  }
  __syncthreads();
  if (tid == 0) {
    double mean[4];
    for (int j = 0; j < 4; j++) mean[j] = sD[j] / (double)n;
    double cov[4][4]; int t4 = 4;
    for (int i = 0; i < 4; i++)
      for (int j = i; j < 4; j++) {
        double c = (sD[t4] - (double)n * mean[i] * mean[j]) / (double)(n - 1);
        if (i == j) c += 1e-6;
        cov[i][j] = c; cov[j][i] = c; t4++;
      }
    double L[4][4] = {};
    for (int i = 0; i < 4; i++)
      for (int j = 0; j <= i; j++) {
        double s = cov[i][j];
        for (int k = 0; k < j; k++) s -= L[i][k] * L[j][k];
        if (i == j) L[i][j] = sqrt(s);
        else        L[i][j] = s / L[j][j];
      }
    for (int i = 0; i < 4; i++) {
      sML[i] = (float)mean[i];
      for (int j = 0; j < 4; j++) sML[4 + i*4 + j] = (float)L[i][j];
    }
    float qlo = sQR[0], qhi = sQR[1], rlo = sQR[2], rhi = sQR[3];
    sML[20] = qlo; sML[21] = (float)BINS / (qhi - qlo);
    sML[22] = rlo; sML[23] = (float)BINS / (rhi - rlo);
  }
  __syncthreads();
}

// ============ k_A: cov raw moments + q/r min-max partials; init encs/ticket
__global__ void __launch_bounds__(256)
k_A(const float* __restrict__ q, const float* __restrict__ r, int n,
    double* Bpart, float* QRmm, unsigned* encs, unsigned* ticket) {
  double a[14] = {0,0,0,0,0,0,0,0,0,0,0,0,0,0};
  float qmn = FLT_MAX, qmx = -FLT_MAX, rmn = FLT_MAX, rmx = -FLT_MAX;
  int stride = gridDim.x * blockDim.x;
  for (int i = blockIdx.x * blockDim.x + threadIdx.x; i < n; i += stride) {
    float2 qv = ((const float2*)q)[i];
    float2 rv = ((const float2*)r)[i];
    qmn = fminf(qmn, fminf(qv.x, qv.y)); qmx = fmaxf(qmx, fmaxf(qv.x, qv.y));
    rmn = fminf(rmn, fminf(rv.x, rv.y)); rmx = fmaxf(rmx, fmaxf(rv.x, rv.y));
    double x0 = qv.x, x1 = qv.y, x2 = rv.x, x3 = rv.y;
    a[0] += x0; a[1] += x1; a[2] += x2; a[3] += x3;
    a[4] += x0*x0; a[5] += x0*x1; a[6] += x0*x2; a[7] += x0*x3;
    a[8] += x1*x1; a[9] += x1*x2; a[10] += x1*x3;
    a[11] += x2*x2; a[12] += x2*x3; a[13] += x3*x3;
  }
  __shared__ double sh[4][14];
  __shared__ float shf[4][4];
  int lane = threadIdx.x & 63, wid = threadIdx.x >> 6;
  for (int j = 0; j < 14; j++) {
    double v = a[j];
    for (int o = 32; o > 0; o >>= 1) v += __shfl_down(v, o);
    if (lane == 0) sh[wid][j] = v;
  }
  for (int o = 32; o > 0; o >>= 1) {
    qmn = fminf(qmn, __shfl_down(qmn, o)); qmx = fmaxf(qmx, __shfl_down(qmx, o));
    rmn = fminf(rmn, __shfl_down(rmn, o)); rmx = fmaxf(rmx, __shfl_down(rmx, o));
  }
  if (lane == 0) { shf[wid][0] = qmn; shf[wid][1] = qmx; shf[wid][2] = rmn; shf[wid][3] = rmx; }
  __syncthreads();
  if (threadIdx.x < 14) {
    double t = sh[0][threadIdx.x] + sh[1][threadIdx.x] + sh[2][threadIdx.x] + sh[3][threadIdx.x];
    Bpart[threadIdx.x * NCH + blockIdx.x] = t;
  } else if (threadIdx.x >= 16 && threadIdx.x < 20) {
    int k = threadIdx.x - 16;
    float v;
    if (k == 0)      v = fminf(fminf(shf[0][0], shf[1][0]), fminf(shf[2][0], shf[3][0]));
    else if (k == 1) v = fmaxf(fmaxf(shf[0][1], shf[1][1]), fmaxf(shf[2][1], shf[3][1]));
    else if (k == 2) v = fminf(fminf(shf[0][2], shf[1][2]), fminf(shf[2][2], shf[3][2]));
    else             v = fmaxf(fmaxf(shf[0][3], shf[1][3]), fmaxf(shf[2][3], shf[3][3]));
    QRmm[k * NCH + blockIdx.x] = v;
  } else if (blockIdx.x == 0 && threadIdx.x == 32) {
    encs[0] = 0xFFFFFFFFu; encs[1] = 0u;
    ticket[0] = 0u;
  }
}

// ============ k_C: redundant reduce+Cholesky; blocks<NZB: sample minmax;
//              blocks >=NZB: marginal QR histograms (partials)
__global__ void __launch_bounds__(1024)
k_C(const double* __restrict__ Bpart, const float* __restrict__ QRmm,
    const float* __restrict__ z, int S,
    const float* __restrict__ q, const float* __restrict__ r, int n,
    float* meanL, unsigned* encs, unsigned* Qpart, unsigned* Rpart) {
  __shared__ double sD[14];
  __shared__ float sQR[4];
  __shared__ float sML[24];
  __shared__ int shQ[2500];
  __shared__ int shR[2500];
  reduce_and_chol(Bpart, QRmm, n, sD, sQR, sML);
  int tid = threadIdx.x, bid = blockIdx.x;
  if (tid == 0 && bid == 0) {    // publish for k_DF
    for (int i = 0; i < 24; i++) meanL[i] = sML[i];
  }
  if (bid < NZB) {
    float l[16], m[4];
    for (int i = 0; i < 16; i++) l[i] = sML[4 + i];
    for (int i = 0; i < 4;  i++) m[i] = sML[i];
    float mn = FLT_MAX, mx = -FLT_MAX;
    const nfloat4* z4 = (const nfloat4*)z;
    int stride = NZB * NTH;
    for (int i = bid * NTH + tid; i < S; i += stride) {
      nfloat4 zv = z4[i];
      float s0, s1, s2, s3; sample4(zv, l, m, s0, s1, s2, s3);
      mn = fminf(mn, fminf(fminf(s0, s1), fminf(s2, s3)));
      mx = fmaxf(mx, fmaxf(fmaxf(s0, s1), fmaxf(s2, s3)));
    }
    for (int o = 32; o > 0; o >>= 1) {
      mn = fminf(mn, __shfl_down(mn, o)); mx = fmaxf(mx, __shfl_down(mx, o));
    }
    __shared__ float shmn[16], shmx[16];
    int lane = tid & 63, wid = tid >> 6;
    if (lane == 0) { shmn[wid] = mn; shmx[wid] = mx; }
    __syncthreads();
    if (tid == 0) {
      for (int w = 0; w < 16; w++) { mn = fminf(mn, shmn[w]); mx = fmaxf(mx, shmx[w]); }
      atomicMin(&encs[0], encf(mn));
      atomicMax(&encs[1], encf(mx));
    }
  } else {
    int qb = bid - NZB;    // 0..15
    for (int i = tid; i < 2500; i += NTH) { shQ[i] = 0; shR[i] = 0; }
    __syncthreads();
    float qlo = sML[20], qsc = sML[21], rlo = sML[22], rsc = sML[23];
    int stride = NQRB * NTH;
    for (int i = qb * NTH + tid; i < n; i += stride) {
      float2 qv = ((const float2*)q)[i];
      float2 rv = ((const float2*)r)[i];
      int a = min(max((int)floorf((qv.x - qlo) * qsc), 0), BINS - 1);
      int b = min(max((int)floorf((qv.y - qlo) * qsc), 0), BINS - 1);
      atomicAdd(&shQ[a*BINS + b], 1);
      a = min(max((int)floorf((rv.x - rlo) * rsc), 0), BINS - 1);
      b = min(max((int)floorf((rv.y - rlo) * rsc), 0), BINS - 1);
      atomicAdd(&shR[a*BINS + b], 1);
    }
    __syncthreads();
    for (int i = tid; i < 2500; i += NTH) {
      Qpart[qb*2500 + i] = (unsigned)shQ[i];
      Rpart[qb*2500 + i] = (unsigned)shR[i];
    }
  }
}

// ============ k_DF: bin own chunk + LDS counting sort (512 buckets) +
//              coalesced chunk write; exports per-chunk bucket prefix (Pfx)
__global__ void __launch_bounds__(1024)
k_DF(const float* __restrict__ z, int S,
     const float* __restrict__ meanL, const unsigned* __restrict__ encs,
     unsigned short* __restrict__ payload, unsigned* __restrict__ Cnt,
     unsigned* __restrict__ Pfx) {
  __shared__ unsigned short ptmp[KCAP];    // 15872 B
  __shared__ unsigned short pays[KCAP];    // 15872 B
  __shared__ unsigned short bb[KCAP];      // 15872 B (bucket 0..511)
  __shared__ unsigned cnt[NBK], sA[NBK], lbase[NBK], cursor[NBK];  // 8192 B
  __shared__ float sL[16], sM[4], sPar[2];
  int tid = threadIdx.x, bid = blockIdx.x;
  if (tid < 16) sL[tid] = meanL[4 + tid];
  if (tid < 4)  sM[tid] = meanL[tid];
  if (tid < NBK) cnt[tid] = 0;
  if (tid == 0) {
    float lo = decf(encs[0]), hi = decf(encs[1]);
    sPar[0] = lo; sPar[1] = (float)BINS / (hi - lo);
  }
  __syncthreads();
  float lo = sPar[0], sc = sPar[1];
  int st = bid * CHUNK;
  int en = min(st + CHUNK, S);
  int len = en - st;
  const nfloat4* z4 = (const nfloat4*)z;
  for (int j = tid; j < len; j += NTH) {
    nfloat4 zv = z4[st + j];
    float s0, s1, s2, s3; sample4(zv, sL, sM, s0, s1, s2, s3);
    int i0 = min(max((int)floorf((s0 - lo) * sc), 0), BINS - 1);
    int i1 = min(max((int)floorf((s1 - lo) * sc), 0), BINS - 1);
    int i2 = min(max((int)floorf((s2 - lo) * sc), 0), BINS - 1);
    int i3 = min(max((int)floorf((s3 - lo) * sc), 0), BINS - 1);
    unsigned flat = (unsigned)(((i0*BINS + i1)*BINS + i2)*BINS + i3);
    ptmp[j] = (unsigned short)(flat >> 9);     // slice index < 12208
    bb[j]   = (unsigned short)(flat & 511u);   // bucket
    atomicAdd(&cnt[flat & 511u], 1u);
  }
  __syncthreads();
  if (tid < NBK) sA[tid] = cnt[tid];
  __syncthreads();
  for (int off = 1; off < NBK; off <<= 1) {
    unsigned x = (tid < NBK && tid >= off) ? sA[tid - off] : 0u;
    __syncthreads();
    if (tid < NBK) sA[tid] += x;
    __syncthreads();
  }
  if (tid < NBK) { lbase[tid] = sA[tid] - cnt[tid]; cursor[tid] = 0; }
  __syncthreads();
  for (int j = tid; j < len; j += NTH) {
    unsigned b = bb[j];
    unsigned pos = lbase[b] + atomicAdd(&cursor[b], 1u);
    pays[pos] = ptmp[j];
  }
  __syncthreads();
  for (int p = tid; p < len; p += NTH) payload[st + p] = pays[p];  // coalesced
  if (tid < NBK) {
    Cnt[bid * NBK + tid] = cnt[tid];
    Pfx[bid * NBK + tid] = lbase[tid];   // free: already computed for the sort
  }
}

// ============ k_G: per-bucket coalesced-run gather + LDS hist + entropy;
//              512 blocks (2/CU); last block finalizes
__global__ void __launch_bounds__(1024)
k_G(const unsigned short* __restrict__ payload, const unsigned* __restrict__ Cnt,
    const unsigned* __restrict__ Pfx,
    const unsigned* __restrict__ Qpart, const unsigned* __restrict__ Rpart,
    double* sumJpart, unsigned* ticket, int n, int S, float* out) {
  __shared__ unsigned shist[SWORDS2];   // 24416 B
  __shared__ unsigned sA[NCH], sBv[NCH];
  __shared__ double sRed[48];
  __shared__ unsigned sFlag;
  int tid = threadIdx.x, bid = blockIdx.x;
  int lane = tid & 63, wv = tid >> 6;
  if (tid < NCH) {                       // 1-iteration column loads (no serial scan)
    sBv[tid] = Pfx[tid * NBK + bid];
    sA[tid]  = Cnt[tid * NBK + bid];
  }
  for (int i = tid; i < SWORDS2; i += NTH) shist[i] = 0u;
  __syncthreads();
  {
    // quarter-wave (16 lanes) per chunk-run: contiguous, 1-2 transactions/run
    int kl = lane & 15;
    int cq = (wv << 2) + (lane >> 4);    // wave's 4 chunks per round
    for (int rnd = 0; rnd < 4; rnd++) {
      int c = (rnd << 6) + cq;           // 64 chunks per round
      unsigned base2 = (unsigned)(c * CHUNK) + sBv[c];
      unsigned lenc = sA[c];
      for (unsigned k = kl; k < lenc; k += 16) {
        unsigned p = payload[base2 + k];  // < 12208
        atomicAdd(&shist[p >> 1], (p & 1u) ? 65536u : 1u);
      }
    }
  }
  __syncthreads();
  double local = 0.0;
  for (int i = tid; i < SWORDS2; i += NTH) {
    unsigned w = shist[i];
    unsigned c0 = w & 0xFFFFu, c1 = w >> 16;
    if (c0 > 1) local += (double)c0 * log((double)c0);
    if (c1 > 1) local += (double)c1 * log((double)c1);
  }
  for (int o = 32; o > 0; o >>= 1) local += __shfl_down(local, o);
  if (lane == 0) sRed[wv] = local;
  __syncthreads();
  if (tid == 0) {
    double s = 0; for (int w = 0; w < 16; w++) s += sRed[w];
    sumJpart[bid] = s;
    __threadfence();
    sFlag = (atomicAdd(ticket, 1u) == NBK - 1) ? 1u : 0u;
  }
  __syncthreads();
  if (!sFlag) return;
  // ---------- last block: final reduction + output ----------
  __threadfence();
  double v = 0.0;
  if (tid < NBK)
    v = __hip_atomic_load(&sumJpart[tid], __ATOMIC_RELAXED, __HIP_MEMORY_SCOPE_AGENT);
  for (int o = 32; o > 0; o >>= 1) v += __shfl_down(v, o);
  if (lane == 0) sRed[wv] = v;
  double lq = 0.0, lr = 0.0;
  for (int bin = tid; bin < 2500; bin += NTH) {
    unsigned cq = 0, cr = 0;
    for (int k = 0; k < NQRB; k++) { cq += Qpart[k*2500 + bin]; cr += Rpart[k*2500 + bin]; }
    if (cq > 1) lq += (double)cq * log((double)cq);
    if (cr > 1) lr += (double)cr * log((double)cr);
  }
  for (int o = 32; o > 0; o >>= 1) { lq += __shfl_down(lq, o); lr += __shfl_down(lr, o); }
  if (lane == 0) { sRed[16 + wv] = lq; sRed[32 + wv] = lr; }
  __syncthreads();
  if (tid == 0) {
    double sJ = 0, sq = 0, sr = 0;
    for (int w = 0; w < 16; w++) { sJ += sRed[w]; sq += sRed[16+w]; sr += sRed[32+w]; }
    double HT = log((double)n) - sq / (double)n;
    double HI = log((double)n) - sr / (double)n;
    double HJ = log((double)S) - sJ / (double)S;
    double val = HJ / (HT + HI);
    val = val < 0.0 ? 0.0 : (val > 1.0 ? 1.0 : val);
    out[0] = (float)val;
  }
}

extern "C" void kernel_launch(void* const* d_in, const int* in_sizes, int n_in,
                              void* d_out, int out_size, void* d_ws, size_t ws_size,
                              hipStream_t stream) {
  const float* q = (const float*)d_in[0];
  const float* r = (const float*)d_in[1];
  const float* z = (const float*)d_in[2];
  int N = in_sizes[0] / 2;   // 200000 rows
  int S = in_sizes[2] / 4;   // 2000000 samples

  // workspace layout (bytes), total ~5.4 MB:
  char* base = (char*)d_ws;
  double*   Bpart    = (double*)base;                     //       0: [14][256]
  float*    QRmm     = (float*)(base + 28672);            //   28672: [4][256]
  float*    meanL    = (float*)(base + 32768);            //   32768: [24]
  unsigned* encs     = (unsigned*)(base + 32896);         //   32896: [2]
  unsigned* ticket   = (unsigned*)(base + 32904);         //   32904: [1]
  double*   sumJpart = (double*)(base + 33024);           //   33024: [512]
  unsigned* Qpart    = (unsigned*)(base + 37120);         //   37120: [16][2500]
  unsigned* Rpart    = (unsigned*)(base + 197120);        //  197120: [16][2500]
  unsigned* Cnt      = (unsigned*)(base + 357120);        //  357120: [256][512]
  unsigned* Pfx      = (unsigned*)(base + 881408);        //  881408: [256][512]
  unsigned short* payload = (unsigned short*)(base + 1405696); // [2M] chunk-sorted (4 MB)

  k_A<<<NCH, 256, 0, stream>>>(q, r, N, Bpart, QRmm, encs, ticket);
  k_C<<<NZB + NQRB, 1024, 0, stream>>>(Bpart, QRmm, z, S, q, r, N,
                                       meanL, encs, Qpart, Rpart);
  k_DF<<<NCH, 1024, 0, stream>>>(z, S, meanL, encs, payload, Cnt, Pfx);
  k_G<<<NBK, 1024, 0, stream>>>(payload, Cnt, Pfx, Qpart, Rpart,
                                sumJpart, ticket, N, S, (float*)d_out);
}